// Round 9
// baseline (687.504 us; speedup 1.0000x reference)
//
#include <hip/hip_runtime.h>
#include <math.h>

#define IN_F   50
#define HID    256
#define OUT_F  121
#define N_LAYERS 4
#define K0PAD  64

typedef __attribute__((ext_vector_type(8))) short short8;
typedef __attribute__((ext_vector_type(4))) float f32x4;

#define GLOBAL_AS __attribute__((address_space(1)))
#define LDS_AS    __attribute__((address_space(3)))

__device__ __forceinline__ ushort f2bf(float f) {
    union { float f; unsigned u; } c; c.f = f;
    unsigned u = c.u;
    u += 0x7fffu + ((u >> 16) & 1u);
    return (ushort)(u >> 16);
}
__device__ __forceinline__ float bf2f(ushort u) {
    union { unsigned u; float f; } c; c.u = ((unsigned)u) << 16;
    return c.f;
}

// ---------------- prep: all weight converts + counts zero, one kernel ----------------
__global__ __launch_bounds__(256) void prep_kernel(
        const float* __restrict__ x, const float* __restrict__ w0,
        const float* __restrict__ W, const float* __restrict__ w1,
        ushort* __restrict__ x_bf, ushort* __restrict__ wt0,
        ushort* __restrict__ Wt, ushort* __restrict__ wt1,
        int* __restrict__ counts, int n) {
    long long flat = (long long)blockIdx.x * 256 + threadIdx.x;
    long long r0 = (long long)n * K0PAD;
    if (flat < r0) {                       // x -> x_bf padded to K=64
        int nd = (int)(flat >> 6), k = (int)(flat & 63);
        x_bf[flat] = (k < IN_F) ? f2bf(x[(size_t)nd * IN_F + k]) : 0;
        return;
    }
    flat -= r0;
    if (flat < HID * K0PAD) {              // lin0_w transpose
        int nn = (int)(flat >> 6), k = (int)(flat & 63);
        wt0[flat] = (k < IN_F) ? f2bf(w0[(size_t)k * HID + nn]) : 0;
        return;
    }
    flat -= HID * K0PAD;
    if (flat < N_LAYERS * HID * HID) {     // W fold beta + transpose (plain [l][n][k])
        int l = (int)(flat >> 16);
        int rem = (int)(flat & 65535);
        int nn = rem >> 8, k = rem & 255;
        float beta = logf(0.5f / (float)(l + 1) + 1.0f);
        float v = beta * W[(size_t)l * HID * HID + (size_t)k * HID + nn];
        if (k == nn) v += 1.0f - beta;
        Wt[flat] = f2bf(v);
        return;
    }
    flat -= N_LAYERS * HID * HID;
    if (flat < 128 * HID) {                // lin1_w transpose, pad 121->128
        int nn = (int)(flat >> 8), k = (int)(flat & 255);
        wt1[flat] = (nn < OUT_F) ? f2bf(w1[(size_t)k * OUT_F + nn]) : 0;
        return;
    }
    flat -= 128 * HID;
    if (flat < n) counts[flat] = 0;
}

// ---------------- CSR build ----------------
__global__ void hist_kernel(const int* __restrict__ dst, int* __restrict__ counts, int E) {
    int e = blockIdx.x * blockDim.x + threadIdx.x;
    if (e < E) atomicAdd(&counts[dst[e]], 1);
}

__global__ void scan_phase1(const int* __restrict__ counts, int* __restrict__ row_ptr,
                            int* __restrict__ bsum, int n) {
    __shared__ int sd[1024];
    int t = threadIdx.x;
    int i = blockIdx.x * 1024 + t;
    int v = (i < n) ? counts[i] : 0;
    sd[t] = v;
    __syncthreads();
    for (int off = 1; off < 1024; off <<= 1) {
        int tmp = (t >= off) ? sd[t - off] : 0;
        __syncthreads();
        sd[t] += tmp;
        __syncthreads();
    }
    if (i < n) row_ptr[i] = sd[t] - v;
    if (t == 1023) bsum[blockIdx.x] = sd[1023];
}

__global__ void scan_phase2(int* __restrict__ bsum, int nb) {
    __shared__ int sd[64];
    int t = threadIdx.x;
    int v = (t < nb) ? bsum[t] : 0;
    sd[t] = v;
    __syncthreads();
    for (int off = 1; off < 64; off <<= 1) {
        int tmp = (t >= off) ? sd[t - off] : 0;
        __syncthreads();
        sd[t] += tmp;
        __syncthreads();
    }
    if (t < nb) bsum[t] = sd[t] - v;
    if (t == nb - 1) bsum[nb] = sd[t];
}

__global__ void scan_phase3(int* __restrict__ row_ptr, int* __restrict__ cursor,
                            const int* __restrict__ bsum, int n, int nb) {
    int i = blockIdx.x * 1024 + threadIdx.x;
    if (i < n) {
        int v = row_ptr[i] + bsum[blockIdx.x];
        row_ptr[i] = v;
        cursor[i]  = v;
    }
    if (i == n - 1) row_ptr[n] = bsum[nb];
}

__global__ void scatter_kernel(const int* __restrict__ src, const int* __restrict__ dst,
                               const float* __restrict__ ew, int* __restrict__ cursor,
                               int* __restrict__ col, float* __restrict__ wv, int E) {
    int e = blockIdx.x * blockDim.x + threadIdx.x;
    if (e < E) {
        int d = dst[e];
        int pos = atomicAdd(&cursor[d], 1);
        col[pos] = src[e];
        wv[pos] = ew[e];
    }
}

// ---------------- lin0 MFMA: x0 = relu(x_bf @ Wt0^T + b), K=64 ----------------
__global__ __launch_bounds__(256) void lin0_mfma(
        const ushort* __restrict__ x_bf, const ushort* __restrict__ wt0,
        const float* __restrict__ b, ushort* __restrict__ x0_bf,
        ushort* __restrict__ h_bf, int M) {
    __shared__ ushort As[4][128][8];
    __shared__ ushort Bs[4][128][8];
    int tid = threadIdx.x;
    int wave = tid >> 6;
    int lane = tid & 63;
    int r16 = lane & 15, q = lane >> 4;
    int bm = blockIdx.x * 128;
    int bn = blockIdx.y * 128;
    int wm = (wave >> 1) * 64, wn = (wave & 1) * 64;

    f32x4 acc[4][4] = {};

    int srow = tid & 127;
    int koff0 = tid >> 7;
    int arow = bm + srow; if (arow >= M) arow = M - 1;
    const ushort* aptr = x_bf + (size_t)arow * K0PAD;
    const ushort* bptr = wt0 + (size_t)(bn + srow) * K0PAD;
    char* AsB = (char*)&As[0][0][0];
    char* BsB = (char*)&Bs[0][0][0];
    int woff = wave * 1024;

    const short8* As8 = (const short8*)&As[0][0][0];
    const short8* Bs8 = (const short8*)&Bs[0][0][0];

    for (int k0 = 0; k0 < K0PAD; k0 += 32) {
        __builtin_amdgcn_global_load_lds((const GLOBAL_AS void*)(aptr + k0 + koff0 * 8),
                                         (LDS_AS void*)(AsB + woff), 16, 0, 0);
        __builtin_amdgcn_global_load_lds((const GLOBAL_AS void*)(aptr + k0 + (koff0 + 2) * 8),
                                         (LDS_AS void*)(AsB + 4096 + woff), 16, 0, 0);
        __builtin_amdgcn_global_load_lds((const GLOBAL_AS void*)(bptr + k0 + koff0 * 8),
                                         (LDS_AS void*)(BsB + woff), 16, 0, 0);
        __builtin_amdgcn_global_load_lds((const GLOBAL_AS void*)(bptr + k0 + (koff0 + 2) * 8),
                                         (LDS_AS void*)(BsB + 4096 + woff), 16, 0, 0);
        __syncthreads();

        short8 av[4], bv[4];
#pragma unroll
        for (int mf = 0; mf < 4; ++mf)
            av[mf] = As8[q * 128 + wm + mf * 16 + r16];
#pragma unroll
        for (int nf = 0; nf < 4; ++nf)
            bv[nf] = Bs8[q * 128 + wn + nf * 16 + r16];
#pragma unroll
        for (int mf = 0; mf < 4; ++mf)
#pragma unroll
            for (int nf = 0; nf < 4; ++nf)
                acc[mf][nf] = __builtin_amdgcn_mfma_f32_16x16x32_bf16(av[mf], bv[nf], acc[mf][nf], 0, 0, 0);
        __syncthreads();
    }

#pragma unroll
    for (int mf = 0; mf < 4; ++mf) {
#pragma unroll
        for (int j = 0; j < 4; ++j) {
            int row = bm + wm + mf * 16 + q * 4 + j;
            if (row >= M) continue;
#pragma unroll
            for (int nf = 0; nf < 4; ++nf) {
                int c = bn + wn + nf * 16 + r16;
                size_t idx = (size_t)row * HID + c;
                ushort v = f2bf(fmaxf(acc[mf][nf][j] + b[c], 0.f));
                x0_bf[idx] = v;
                h_bf[idx]  = v;
            }
        }
    }
}

// ---- SpMM + alpha mix, XCD-affine feature slices ----
// blockIdx.x & 7 = feature slice (32 cols, 64B/row): consecutive blocks round-robin
// across the 8 XCDs -> each XCD's L2 sees a 3.2MB column slice of h (fits 4MB).
// Wave: 4 edge slots x 16 lanes (2 features each); shfl_xor(16,32) combines slots.
__global__ __launch_bounds__(256) void spmm_mix_kernel(
        const int* __restrict__ row_ptr, const int* __restrict__ col,
        const float* __restrict__ wv, const ushort* __restrict__ h_bf,
        const ushort* __restrict__ x0_bf, ushort* __restrict__ s_bf, int n) {
    int slice = blockIdx.x & 7;
    int ng    = blockIdx.x >> 3;
    int wave  = threadIdx.x >> 6;
    int lane  = threadIdx.x & 63;
    int sub   = lane >> 4;               // edge slot 0..3
    int fl    = lane & 15;
    int fcol  = slice * 32 + fl * 2;
    int node0 = (ng * 4 + wave) * 8;
    for (int i = 0; i < 8; ++i) {
        int node = node0 + i;
        if (node >= n) return;
        int beg = row_ptr[node], end = row_ptr[node + 1];
        float a0 = 0.f, a1 = 0.f;
        for (int e = beg; e < end; e += 4) {
            int ee = e + sub;
            int ce = (ee < end) ? ee : e;
            float w = (ee < end) ? wv[ee] : 0.f;
            int c = col[ce];
            ushort2 v = *reinterpret_cast<const ushort2*>(&h_bf[(size_t)c * HID + fcol]);
            a0 = fmaf(w, bf2f(v.x), a0);
            a1 = fmaf(w, bf2f(v.y), a1);
        }
        a0 += __shfl_xor(a0, 16, 64); a0 += __shfl_xor(a0, 32, 64);
        a1 += __shfl_xor(a1, 16, 64); a1 += __shfl_xor(a1, 32, 64);
        if (sub == 0) {
            size_t idx = (size_t)node * HID + fcol;
            ushort2 xv = *reinterpret_cast<const ushort2*>(&x0_bf[idx]);
            ushort2 r;
            r.x = f2bf(0.9f * a0 + 0.1f * bf2f(xv.x));
            r.y = f2bf(0.9f * a1 + 0.1f * bf2f(xv.y));
            *reinterpret_cast<ushort2*>(&s_bf[idx]) = r;
        }
    }
}

// ---------------- MFMA layer GEMM: h_bf = relu(s @ W' + h_bf), 128x128 ----------------
__global__ __launch_bounds__(256) void gemm_mfma_layer(
        const ushort* __restrict__ s_bf, const ushort* __restrict__ wt,
        ushort* __restrict__ h_bf, int M) {
    __shared__ ushort As[4][128][8];
    __shared__ ushort Bs[4][128][8];
    int tid = threadIdx.x;
    int wave = tid >> 6;
    int lane = tid & 63;
    int r16 = lane & 15, q = lane >> 4;
    int bm = blockIdx.x * 128;
    int bn = blockIdx.y * 128;
    int wm = (wave >> 1) * 64, wn = (wave & 1) * 64;

    f32x4 acc[4][4] = {};

    int srow = tid & 127;
    int koff0 = tid >> 7;
    int arow = bm + srow; if (arow >= M) arow = M - 1;
    const ushort* aptr = s_bf + (size_t)arow * HID;
    const ushort* bptr = wt + (size_t)(bn + srow) * HID;
    char* AsB = (char*)&As[0][0][0];
    char* BsB = (char*)&Bs[0][0][0];
    int woff = wave * 1024;

    const short8* As8 = (const short8*)&As[0][0][0];
    const short8* Bs8 = (const short8*)&Bs[0][0][0];

    for (int k0 = 0; k0 < HID; k0 += 32) {
        __builtin_amdgcn_global_load_lds((const GLOBAL_AS void*)(aptr + k0 + koff0 * 8),
                                         (LDS_AS void*)(AsB + woff), 16, 0, 0);
        __builtin_amdgcn_global_load_lds((const GLOBAL_AS void*)(aptr + k0 + (koff0 + 2) * 8),
                                         (LDS_AS void*)(AsB + 4096 + woff), 16, 0, 0);
        __builtin_amdgcn_global_load_lds((const GLOBAL_AS void*)(bptr + k0 + koff0 * 8),
                                         (LDS_AS void*)(BsB + woff), 16, 0, 0);
        __builtin_amdgcn_global_load_lds((const GLOBAL_AS void*)(bptr + k0 + (koff0 + 2) * 8),
                                         (LDS_AS void*)(BsB + 4096 + woff), 16, 0, 0);
        __syncthreads();

        short8 av[4], bv[4];
#pragma unroll
        for (int mf = 0; mf < 4; ++mf)
            av[mf] = As8[q * 128 + wm + mf * 16 + r16];
#pragma unroll
        for (int nf = 0; nf < 4; ++nf)
            bv[nf] = Bs8[q * 128 + wn + nf * 16 + r16];
#pragma unroll
        for (int mf = 0; mf < 4; ++mf)
#pragma unroll
            for (int nf = 0; nf < 4; ++nf)
                acc[mf][nf] = __builtin_amdgcn_mfma_f32_16x16x32_bf16(av[mf], bv[nf], acc[mf][nf], 0, 0, 0);
        __syncthreads();
    }

#pragma unroll
    for (int mf = 0; mf < 4; ++mf) {
#pragma unroll
        for (int j = 0; j < 4; ++j) {
            int row = bm + wm + mf * 16 + q * 4 + j;
            if (row >= M) continue;
#pragma unroll
            for (int nf = 0; nf < 4; ++nf) {
                int c = bn + wn + nf * 16 + r16;
                size_t idx = (size_t)row * HID + c;
                float v = fmaxf(acc[mf][nf][j] + bf2f(h_bf[idx]), 0.f);
                h_bf[idx] = f2bf(v);
            }
        }
    }
}

// ---------------- MFMA lin1: out = h @ lin1_w + b ----------------
__global__ __launch_bounds__(256) void lin1_mfma(
        const ushort* __restrict__ h_bf, const ushort* __restrict__ wt1,
        const float* __restrict__ b, float* __restrict__ out, int M) {
    __shared__ ushort As[4][128][8];
    __shared__ ushort Bs[4][128][8];
    int tid = threadIdx.x;
    int wave = tid >> 6;
    int lane = tid & 63;
    int r16 = lane & 15, q = lane >> 4;
    int bm = blockIdx.x * 128;
    int wm = (wave >> 1) * 64, wn = (wave & 1) * 64;

    f32x4 acc[4][4] = {};

    int srow = tid & 127;
    int koff0 = tid >> 7;
    int arow = bm + srow; if (arow >= M) arow = M - 1;
    const ushort* aptr = h_bf + (size_t)arow * HID;
    const ushort* bptr = wt1 + (size_t)srow * HID;
    char* AsB = (char*)&As[0][0][0];
    char* BsB = (char*)&Bs[0][0][0];
    int woff = wave * 1024;

    const short8* As8 = (const short8*)&As[0][0][0];
    const short8* Bs8 = (const short8*)&Bs[0][0][0];

    for (int k0 = 0; k0 < HID; k0 += 32) {
        __builtin_amdgcn_global_load_lds((const GLOBAL_AS void*)(aptr + k0 + koff0 * 8),
                                         (LDS_AS void*)(AsB + woff), 16, 0, 0);
        __builtin_amdgcn_global_load_lds((const GLOBAL_AS void*)(aptr + k0 + (koff0 + 2) * 8),
                                         (LDS_AS void*)(AsB + 4096 + woff), 16, 0, 0);
        __builtin_amdgcn_global_load_lds((const GLOBAL_AS void*)(bptr + k0 + koff0 * 8),
                                         (LDS_AS void*)(BsB + woff), 16, 0, 0);
        __builtin_amdgcn_global_load_lds((const GLOBAL_AS void*)(bptr + k0 + (koff0 + 2) * 8),
                                         (LDS_AS void*)(BsB + 4096 + woff), 16, 0, 0);
        __syncthreads();

        short8 av[4], bv[4];
#pragma unroll
        for (int mf = 0; mf < 4; ++mf)
            av[mf] = As8[q * 128 + wm + mf * 16 + r16];
#pragma unroll
        for (int nf = 0; nf < 4; ++nf)
            bv[nf] = Bs8[q * 128 + wn + nf * 16 + r16];
#pragma unroll
        for (int mf = 0; mf < 4; ++mf)
#pragma unroll
            for (int nf = 0; nf < 4; ++nf)
                acc[mf][nf] = __builtin_amdgcn_mfma_f32_16x16x32_bf16(av[mf], bv[nf], acc[mf][nf], 0, 0, 0);
        __syncthreads();
    }

#pragma unroll
    for (int mf = 0; mf < 4; ++mf) {
#pragma unroll
        for (int j = 0; j < 4; ++j) {
            int row = bm + wm + mf * 16 + q * 4 + j;
            if (row >= M) continue;
#pragma unroll
            for (int nf = 0; nf < 4; ++nf) {
                int c = wn + nf * 16 + r16;
                if (c < OUT_F)
                    out[(size_t)row * OUT_F + c] = acc[mf][nf][j] + b[c];
            }
        }
    }
}

extern "C" void kernel_launch(void* const* d_in, const int* in_sizes, int n_in,
                              void* d_out, int out_size, void* d_ws, size_t ws_size,
                              hipStream_t stream) {
    const float* x      = (const float*)d_in[0];
    const int*   ei     = (const int*)d_in[1];
    const float* ew     = (const float*)d_in[2];
    const float* lin0_w = (const float*)d_in[3];
    const float* lin0_b = (const float*)d_in[4];
    const float* W      = (const float*)d_in[5];
    const float* lin1_w = (const float*)d_in[6];
    const float* lin1_b = (const float*)d_in[7];
    float* out = (float*)d_out;

    int N = in_sizes[0] / IN_F;
    int E = in_sizes[2];
    const int* src = ei;
    const int* dst = ei + E;

    char* ws = (char*)d_ws;
    ushort* x0_bf   = (ushort*)ws; ws += (size_t)N * HID * 2;
    ushort* h_bf    = (ushort*)ws; ws += (size_t)N * HID * 2;
    ushort* s_bf    = (ushort*)ws; ws += (size_t)N * HID * 2;
    ushort* x_bf    = (ushort*)ws; ws += (size_t)N * K0PAD * 2;
    ushort* Wt0     = (ushort*)ws; ws += (size_t)HID * K0PAD * 2;
    ushort* Wt      = (ushort*)ws; ws += (size_t)N_LAYERS * HID * HID * 2;
    ushort* Wt1     = (ushort*)ws; ws += (size_t)128 * HID * 2;
    int*    row_ptr = (int*)ws;    ws += (size_t)(N + 1) * 4;
    int*    counts  = (int*)ws;    ws += (size_t)N * 4;
    int*    cursor  = (int*)ws;    ws += (size_t)N * 4;
    int*    bsum    = (int*)ws;    ws += (size_t)128 * 4;
    int*    col     = (int*)ws;    ws += (size_t)E * 4;
    float*  wv      = (float*)ws;  ws += (size_t)E * 4;

    int nb = (N + 1023) / 1024;

    size_t prep_tot = (size_t)N * K0PAD + HID * K0PAD
                    + (size_t)N_LAYERS * HID * HID + 128 * HID + N;
    prep_kernel<<<(int)((prep_tot + 255) / 256), 256, 0, stream>>>(
        x, lin0_w, W, lin1_w, x_bf, Wt0, Wt, Wt1, counts, N);

    hist_kernel<<<(E + 255) / 256, 256, 0, stream>>>(dst, counts, E);
    scan_phase1<<<nb, 1024, 0, stream>>>(counts, row_ptr, bsum, N);
    scan_phase2<<<1, 64, 0, stream>>>(bsum, nb);
    scan_phase3<<<nb, 1024, 0, stream>>>(row_ptr, cursor, bsum, N, nb);
    scatter_kernel<<<(E + 255) / 256, 256, 0, stream>>>(src, dst, ew, cursor, col, wv, E);

    int mblocks = (N + 127) / 128;
    lin0_mfma<<<dim3(mblocks, 2), 256, 0, stream>>>(x_bf, Wt0, lin0_b, x0_bf, h_bf, N);

    int spmm_blocks = 8 * ((N + 31) / 32);
    for (int l = 0; l < N_LAYERS; ++l) {
        spmm_mix_kernel<<<spmm_blocks, 256, 0, stream>>>(row_ptr, col, wv, h_bf, x0_bf, s_bf, N);
        gemm_mfma_layer<<<dim3(mblocks, 2), 256, 0, stream>>>(
            s_bf, Wt + (size_t)l * HID * HID, h_bf, N);
    }

    lin1_mfma<<<mblocks, 256, 0, stream>>>(h_bf, Wt1, lin1_b, out, N);
}

// Round 10
// 292.449 us; speedup vs baseline: 2.3508x; 2.3508x over previous
//
#include <hip/hip_runtime.h>
#include <math.h>

#define IN_F   50
#define HID    256
#define OUT_F  121
#define N_LAYERS 4
#define K0PAD  64

typedef __attribute__((ext_vector_type(8))) short short8;
typedef __attribute__((ext_vector_type(4))) float f32x4;

#define GLOBAL_AS __attribute__((address_space(1)))
#define LDS_AS    __attribute__((address_space(3)))

__device__ __forceinline__ ushort f2bf(float f) {
    union { float f; unsigned u; } c; c.f = f;
    unsigned u = c.u;
    u += 0x7fffu + ((u >> 16) & 1u);
    return (ushort)(u >> 16);
}
__device__ __forceinline__ float bf2f(ushort u) {
    union { unsigned u; float f; } c; c.u = ((unsigned)u) << 16;
    return c.f;
}

// ---------------- prep: weight converts + counts zero ----------------
// Wt per layer: [ts=K/32][kq=0..3][n=0..255][j=0..7], k = ts*32+kq*8+j
// (contiguous 16KB staging source per K-step)
__global__ __launch_bounds__(256) void prep_kernel(
        const float* __restrict__ x, const float* __restrict__ w0,
        const float* __restrict__ W, const float* __restrict__ w1,
        ushort* __restrict__ x_bf, ushort* __restrict__ wt0,
        ushort* __restrict__ Wt, ushort* __restrict__ wt1,
        int* __restrict__ counts, int n) {
    long long flat = (long long)blockIdx.x * 256 + threadIdx.x;
    long long r0 = (long long)n * K0PAD;
    if (flat < r0) {
        int nd = (int)(flat >> 6), k = (int)(flat & 63);
        x_bf[flat] = (k < IN_F) ? f2bf(x[(size_t)nd * IN_F + k]) : 0;
        return;
    }
    flat -= r0;
    if (flat < HID * K0PAD) {
        int nn = (int)(flat >> 6), k = (int)(flat & 63);
        wt0[flat] = (k < IN_F) ? f2bf(w0[(size_t)k * HID + nn]) : 0;
        return;
    }
    flat -= HID * K0PAD;
    if (flat < N_LAYERS * HID * HID) {
        int l = (int)(flat >> 16);
        int rem = (int)(flat & 65535);
        int ts = rem >> 13;
        int kq = (rem >> 11) & 3;
        int nn = (rem >> 3) & 255;
        int j  = rem & 7;
        int k  = ts * 32 + kq * 8 + j;
        float beta = logf(0.5f / (float)(l + 1) + 1.0f);
        float v = beta * W[(size_t)l * HID * HID + (size_t)k * HID + nn];
        if (k == nn) v += 1.0f - beta;
        Wt[flat] = f2bf(v);
        return;
    }
    flat -= N_LAYERS * HID * HID;
    if (flat < 128 * HID) {
        int nn = (int)(flat >> 8), k = (int)(flat & 255);
        wt1[flat] = (nn < OUT_F) ? f2bf(w1[(size_t)k * OUT_F + nn]) : 0;
        return;
    }
    flat -= 128 * HID;
    if (flat < n) counts[flat] = 0;
}

// ---------------- CSR build ----------------
__global__ void hist_kernel(const int* __restrict__ dst, int* __restrict__ counts, int E) {
    int e = blockIdx.x * blockDim.x + threadIdx.x;
    if (e < E) atomicAdd(&counts[dst[e]], 1);
}

__global__ void scan_phase1(const int* __restrict__ counts, int* __restrict__ row_ptr,
                            int* __restrict__ bsum, int n) {
    __shared__ int sd[1024];
    int t = threadIdx.x;
    int i = blockIdx.x * 1024 + t;
    int v = (i < n) ? counts[i] : 0;
    sd[t] = v;
    __syncthreads();
    for (int off = 1; off < 1024; off <<= 1) {
        int tmp = (t >= off) ? sd[t - off] : 0;
        __syncthreads();
        sd[t] += tmp;
        __syncthreads();
    }
    if (i < n) row_ptr[i] = sd[t] - v;
    if (t == 1023) bsum[blockIdx.x] = sd[1023];
}

__global__ void scan_phase2(int* __restrict__ bsum, int nb) {
    __shared__ int sd[64];
    int t = threadIdx.x;
    int v = (t < nb) ? bsum[t] : 0;
    sd[t] = v;
    __syncthreads();
    for (int off = 1; off < 64; off <<= 1) {
        int tmp = (t >= off) ? sd[t - off] : 0;
        __syncthreads();
        sd[t] += tmp;
        __syncthreads();
    }
    if (t < nb) bsum[t] = sd[t] - v;
    if (t == nb - 1) bsum[nb] = sd[t];
}

__global__ void scan_phase3(int* __restrict__ row_ptr, int* __restrict__ cursor,
                            const int* __restrict__ bsum, int n, int nb) {
    int i = blockIdx.x * 1024 + threadIdx.x;
    if (i < n) {
        int v = row_ptr[i] + bsum[blockIdx.x];
        row_ptr[i] = v;
        cursor[i]  = v;
    }
    if (i == n - 1) row_ptr[n] = bsum[nb];
}

__global__ void scatter_kernel(const int* __restrict__ src, const int* __restrict__ dst,
                               const float* __restrict__ ew, int* __restrict__ cursor,
                               int* __restrict__ col, float* __restrict__ wv, int E) {
    int e = blockIdx.x * blockDim.x + threadIdx.x;
    if (e < E) {
        int d = dst[e];
        int pos = atomicAdd(&cursor[d], 1);
        col[pos] = src[e];
        wv[pos] = ew[e];
    }
}

// ---------------- lin0 MFMA: x0 = relu(x_bf @ Wt0^T + b), K=64 ----------------
__global__ __launch_bounds__(256) void lin0_mfma(
        const ushort* __restrict__ x_bf, const ushort* __restrict__ wt0,
        const float* __restrict__ b, ushort* __restrict__ x0_bf,
        ushort* __restrict__ h_bf, int M) {
    __shared__ ushort As[4][128][8];
    __shared__ ushort Bs[4][128][8];
    int tid = threadIdx.x;
    int wave = tid >> 6;
    int lane = tid & 63;
    int r16 = lane & 15, q = lane >> 4;
    int bm = blockIdx.x * 128;
    int bn = blockIdx.y * 128;
    int wm = (wave >> 1) * 64, wn = (wave & 1) * 64;

    f32x4 acc[4][4] = {};

    int srow = tid & 127;
    int koff0 = tid >> 7;
    int arow = bm + srow; if (arow >= M) arow = M - 1;
    const ushort* aptr = x_bf + (size_t)arow * K0PAD;
    const ushort* bptr = wt0 + (size_t)(bn + srow) * K0PAD;
    char* AsB = (char*)&As[0][0][0];
    char* BsB = (char*)&Bs[0][0][0];
    int woff = wave * 1024;

    const short8* As8 = (const short8*)&As[0][0][0];
    const short8* Bs8 = (const short8*)&Bs[0][0][0];

    for (int k0 = 0; k0 < K0PAD; k0 += 32) {
        __builtin_amdgcn_global_load_lds((const GLOBAL_AS void*)(aptr + k0 + koff0 * 8),
                                         (LDS_AS void*)(AsB + woff), 16, 0, 0);
        __builtin_amdgcn_global_load_lds((const GLOBAL_AS void*)(aptr + k0 + (koff0 + 2) * 8),
                                         (LDS_AS void*)(AsB + 4096 + woff), 16, 0, 0);
        __builtin_amdgcn_global_load_lds((const GLOBAL_AS void*)(bptr + k0 + koff0 * 8),
                                         (LDS_AS void*)(BsB + woff), 16, 0, 0);
        __builtin_amdgcn_global_load_lds((const GLOBAL_AS void*)(bptr + k0 + (koff0 + 2) * 8),
                                         (LDS_AS void*)(BsB + 4096 + woff), 16, 0, 0);
        __syncthreads();

        short8 av[4], bv[4];
#pragma unroll
        for (int mf = 0; mf < 4; ++mf)
            av[mf] = As8[q * 128 + wm + mf * 16 + r16];
#pragma unroll
        for (int nf = 0; nf < 4; ++nf)
            bv[nf] = Bs8[q * 128 + wn + nf * 16 + r16];
#pragma unroll
        for (int mf = 0; mf < 4; ++mf)
#pragma unroll
            for (int nf = 0; nf < 4; ++nf)
                acc[mf][nf] = __builtin_amdgcn_mfma_f32_16x16x32_bf16(av[mf], bv[nf], acc[mf][nf], 0, 0, 0);
        __syncthreads();
    }

#pragma unroll
    for (int mf = 0; mf < 4; ++mf) {
#pragma unroll
        for (int j = 0; j < 4; ++j) {
            int row = bm + wm + mf * 16 + q * 4 + j;
            if (row >= M) continue;
#pragma unroll
            for (int nf = 0; nf < 4; ++nf) {
                int c = bn + wn + nf * 16 + r16;
                size_t idx = (size_t)row * HID + c;
                ushort v = f2bf(fmaxf(acc[mf][nf][j] + b[c], 0.f));
                x0_bf[idx] = v;
                h_bf[idx]  = v;
            }
        }
    }
}

// -------- SpMM + alpha mix (r4 proven form): wave/node, ushort4/lane, 4-edge unroll ----
__global__ __launch_bounds__(256) void spmm_mix_kernel(
        const int* __restrict__ row_ptr, const int* __restrict__ col,
        const float* __restrict__ wv, const ushort* __restrict__ h_bf,
        const ushort* __restrict__ x0_bf, ushort* __restrict__ s_bf, int n) {
    int node = (blockIdx.x * 256 + threadIdx.x) >> 6;
    if (node >= n) return;
    int lane = threadIdx.x & 63;
    int f0 = lane * 4;
    int beg = row_ptr[node], end = row_ptr[node + 1];
    float a0 = 0.f, a1 = 0.f, a2 = 0.f, a3 = 0.f;
    int e = beg;
    for (; e + 4 <= end; e += 4) {
        int c0 = col[e], c1 = col[e + 1], c2 = col[e + 2], c3 = col[e + 3];
        float w0 = wv[e], w1 = wv[e + 1], w2 = wv[e + 2], w3 = wv[e + 3];
        ushort4 v0 = *reinterpret_cast<const ushort4*>(&h_bf[(size_t)c0 * HID + f0]);
        ushort4 v1 = *reinterpret_cast<const ushort4*>(&h_bf[(size_t)c1 * HID + f0]);
        ushort4 v2 = *reinterpret_cast<const ushort4*>(&h_bf[(size_t)c2 * HID + f0]);
        ushort4 v3 = *reinterpret_cast<const ushort4*>(&h_bf[(size_t)c3 * HID + f0]);
        a0 = fmaf(w0, bf2f(v0.x), a0); a1 = fmaf(w0, bf2f(v0.y), a1);
        a2 = fmaf(w0, bf2f(v0.z), a2); a3 = fmaf(w0, bf2f(v0.w), a3);
        a0 = fmaf(w1, bf2f(v1.x), a0); a1 = fmaf(w1, bf2f(v1.y), a1);
        a2 = fmaf(w1, bf2f(v1.z), a2); a3 = fmaf(w1, bf2f(v1.w), a3);
        a0 = fmaf(w2, bf2f(v2.x), a0); a1 = fmaf(w2, bf2f(v2.y), a1);
        a2 = fmaf(w2, bf2f(v2.z), a2); a3 = fmaf(w2, bf2f(v2.w), a3);
        a0 = fmaf(w3, bf2f(v3.x), a0); a1 = fmaf(w3, bf2f(v3.y), a1);
        a2 = fmaf(w3, bf2f(v3.z), a2); a3 = fmaf(w3, bf2f(v3.w), a3);
    }
    if (e + 2 <= end) {
        int c0 = col[e], c1 = col[e + 1];
        float w0 = wv[e], w1 = wv[e + 1];
        ushort4 v0 = *reinterpret_cast<const ushort4*>(&h_bf[(size_t)c0 * HID + f0]);
        ushort4 v1 = *reinterpret_cast<const ushort4*>(&h_bf[(size_t)c1 * HID + f0]);
        a0 = fmaf(w0, bf2f(v0.x), a0); a1 = fmaf(w0, bf2f(v0.y), a1);
        a2 = fmaf(w0, bf2f(v0.z), a2); a3 = fmaf(w0, bf2f(v0.w), a3);
        a0 = fmaf(w1, bf2f(v1.x), a0); a1 = fmaf(w1, bf2f(v1.y), a1);
        a2 = fmaf(w1, bf2f(v1.z), a2); a3 = fmaf(w1, bf2f(v1.w), a3);
        e += 2;
    }
    if (e < end) {
        int c0 = col[e];
        float w0 = wv[e];
        ushort4 v0 = *reinterpret_cast<const ushort4*>(&h_bf[(size_t)c0 * HID + f0]);
        a0 = fmaf(w0, bf2f(v0.x), a0); a1 = fmaf(w0, bf2f(v0.y), a1);
        a2 = fmaf(w0, bf2f(v0.z), a2); a3 = fmaf(w0, bf2f(v0.w), a3);
    }
    size_t idx = (size_t)node * HID + f0;
    ushort4 xv = *reinterpret_cast<const ushort4*>(&x0_bf[idx]);
    ushort4 r;
    r.x = f2bf(0.9f * a0 + 0.1f * bf2f(xv.x));
    r.y = f2bf(0.9f * a1 + 0.1f * bf2f(xv.y));
    r.z = f2bf(0.9f * a2 + 0.1f * bf2f(xv.z));
    r.w = f2bf(0.9f * a3 + 0.1f * bf2f(xv.w));
    *reinterpret_cast<ushort4*>(&s_bf[idx]) = r;
}

// ------- layer GEMM BM=128 x BN=256 single-pass: h = relu(s @ W' + h) in-place -------
// As granule-XOR swizzle: dest slot p holds source granule p^((row>>1)&3);
// reader at (row, q) fetches slot q^((row>>1)&3) -> source granule q. Verified algebra.
__global__ __launch_bounds__(512) void gemm_mfma_layer(
        const ushort* __restrict__ s_bf, const ushort* __restrict__ wt,
        ushort* __restrict__ h_bf, int M) {
    __shared__ ushort As[128 * 32];        // 8 KB
    __shared__ ushort Bs[4 * 256 * 8];     // 16 KB
    int tid = threadIdx.x;
    int wave = tid >> 6;
    int lane = tid & 63;
    int r16 = lane & 15, q = lane >> 4;
    int bm = blockIdx.x * 128;
    int wm = (wave >> 2) * 64, wn = (wave & 3) * 64;   // 2x4 wave grid

    f32x4 acc[4][4] = {};

    int arow_l = tid >> 2;                 // 0..127
    int p = tid & 3;                       // dest granule slot
    int gsrc = p ^ ((arow_l >> 1) & 3);    // source granule
    int arow = bm + arow_l; if (arow >= M) arow = M - 1;
    const ushort* aptr = s_bf + (size_t)arow * HID;
    char* AsB = (char*)As;
    char* BsB = (char*)Bs;
    const short8* Bs8 = (const short8*)Bs;

    for (int ts = 0; ts < 8; ++ts) {
        __builtin_amdgcn_global_load_lds((const GLOBAL_AS void*)(aptr + ts * 32 + gsrc * 8),
                                         (LDS_AS void*)(AsB + tid * 16), 16, 0, 0);
        __builtin_amdgcn_global_load_lds((const GLOBAL_AS void*)(wt + (size_t)ts * 8192 + tid * 8),
                                         (LDS_AS void*)(BsB + tid * 16), 16, 0, 0);
        __builtin_amdgcn_global_load_lds((const GLOBAL_AS void*)(wt + (size_t)ts * 8192 + (tid + 512) * 8),
                                         (LDS_AS void*)(BsB + (tid + 512) * 16), 16, 0, 0);
        __syncthreads();

        short8 av[4], bv[4];
#pragma unroll
        for (int mf = 0; mf < 4; ++mf) {
            int row = wm + mf * 16 + r16;
            int g = q ^ ((row >> 1) & 3);
            av[mf] = *reinterpret_cast<const short8*>(AsB + row * 64 + g * 16);
        }
#pragma unroll
        for (int nf = 0; nf < 4; ++nf)
            bv[nf] = Bs8[q * 256 + wn + nf * 16 + r16];
#pragma unroll
        for (int mf = 0; mf < 4; ++mf)
#pragma unroll
            for (int nf = 0; nf < 4; ++nf)
                acc[mf][nf] = __builtin_amdgcn_mfma_f32_16x16x32_bf16(av[mf], bv[nf], acc[mf][nf], 0, 0, 0);
        __syncthreads();
    }

#pragma unroll
    for (int mf = 0; mf < 4; ++mf) {
#pragma unroll
        for (int j = 0; j < 4; ++j) {
            int row = bm + wm + mf * 16 + q * 4 + j;
            if (row >= M) continue;
#pragma unroll
            for (int nf = 0; nf < 4; ++nf) {
                int c = wn + nf * 16 + r16;
                size_t idx = (size_t)row * HID + c;
                float v = fmaxf(acc[mf][nf][j] + bf2f(h_bf[idx]), 0.f);
                h_bf[idx] = f2bf(v);
            }
        }
    }
}

// ---------------- MFMA lin1: out = h @ lin1_w + b ----------------
__global__ __launch_bounds__(256) void lin1_mfma(
        const ushort* __restrict__ h_bf, const ushort* __restrict__ wt1,
        const float* __restrict__ b, float* __restrict__ out, int M) {
    __shared__ ushort As[4][128][8];
    __shared__ ushort Bs[4][128][8];
    int tid = threadIdx.x;
    int wave = tid >> 6;
    int lane = tid & 63;
    int r16 = lane & 15, q = lane >> 4;
    int bm = blockIdx.x * 128;
    int wm = (wave >> 1) * 64, wn = (wave & 1) * 64;

    f32x4 acc[4][4] = {};

    int srow = tid & 127;
    int koff0 = tid >> 7;
    int arow = bm + srow; if (arow >= M) arow = M - 1;
    const ushort* aptr = h_bf + (size_t)arow * HID;
    const ushort* bptr = wt1 + (size_t)srow * HID;
    char* AsB = (char*)&As[0][0][0];
    char* BsB = (char*)&Bs[0][0][0];
    int woff = wave * 1024;

    const short8* As8 = (const short8*)&As[0][0][0];
    const short8* Bs8 = (const short8*)&Bs[0][0][0];

    for (int k0 = 0; k0 < HID; k0 += 32) {
        __builtin_amdgcn_global_load_lds((const GLOBAL_AS void*)(aptr + k0 + koff0 * 8),
                                         (LDS_AS void*)(AsB + woff), 16, 0, 0);
        __builtin_amdgcn_global_load_lds((const GLOBAL_AS void*)(aptr + k0 + (koff0 + 2) * 8),
                                         (LDS_AS void*)(AsB + 4096 + woff), 16, 0, 0);
        __builtin_amdgcn_global_load_lds((const GLOBAL_AS void*)(bptr + k0 + koff0 * 8),
                                         (LDS_AS void*)(BsB + woff), 16, 0, 0);
        __builtin_amdgcn_global_load_lds((const GLOBAL_AS void*)(bptr + k0 + (koff0 + 2) * 8),
                                         (LDS_AS void*)(BsB + 4096 + woff), 16, 0, 0);
        __syncthreads();

        short8 av[4], bv[4];
#pragma unroll
        for (int mf = 0; mf < 4; ++mf)
            av[mf] = As8[q * 128 + wm + mf * 16 + r16];
#pragma unroll
        for (int nf = 0; nf < 4; ++nf)
            bv[nf] = Bs8[q * 128 + wn + nf * 16 + r16];
#pragma unroll
        for (int mf = 0; mf < 4; ++mf)
#pragma unroll
            for (int nf = 0; nf < 4; ++nf)
                acc[mf][nf] = __builtin_amdgcn_mfma_f32_16x16x32_bf16(av[mf], bv[nf], acc[mf][nf], 0, 0, 0);
        __syncthreads();
    }

#pragma unroll
    for (int mf = 0; mf < 4; ++mf) {
#pragma unroll
        for (int j = 0; j < 4; ++j) {
            int row = bm + wm + mf * 16 + q * 4 + j;
            if (row >= M) continue;
#pragma unroll
            for (int nf = 0; nf < 4; ++nf) {
                int c = wn + nf * 16 + r16;
                if (c < OUT_F)
                    out[(size_t)row * OUT_F + c] = acc[mf][nf][j] + b[c];
            }
        }
    }
}

extern "C" void kernel_launch(void* const* d_in, const int* in_sizes, int n_in,
                              void* d_out, int out_size, void* d_ws, size_t ws_size,
                              hipStream_t stream) {
    const float* x      = (const float*)d_in[0];
    const int*   ei     = (const int*)d_in[1];
    const float* ew     = (const float*)d_in[2];
    const float* lin0_w = (const float*)d_in[3];
    const float* lin0_b = (const float*)d_in[4];
    const float* W      = (const float*)d_in[5];
    const float* lin1_w = (const float*)d_in[6];
    const float* lin1_b = (const float*)d_in[7];
    float* out = (float*)d_out;

    int N = in_sizes[0] / IN_F;
    int E = in_sizes[2];
    const int* src = ei;
    const int* dst = ei + E;

    char* ws = (char*)d_ws;
    ushort* x0_bf   = (ushort*)ws; ws += (size_t)N * HID * 2;
    ushort* h_bf    = (ushort*)ws; ws += (size_t)N * HID * 2;
    ushort* s_bf    = (ushort*)ws; ws += (size_t)N * HID * 2;
    ushort* x_bf    = (ushort*)ws; ws += (size_t)N * K0PAD * 2;
    ushort* Wt0     = (ushort*)ws; ws += (size_t)HID * K0PAD * 2;
    ushort* Wt      = (ushort*)ws; ws += (size_t)N_LAYERS * HID * HID * 2;
    ushort* Wt1     = (ushort*)ws; ws += (size_t)128 * HID * 2;
    int*    row_ptr = (int*)ws;    ws += (size_t)(N + 1) * 4;
    int*    counts  = (int*)ws;    ws += (size_t)N * 4;
    int*    cursor  = (int*)ws;    ws += (size_t)N * 4;
    int*    bsum    = (int*)ws;    ws += (size_t)128 * 4;
    int*    col     = (int*)ws;    ws += (size_t)E * 4;
    float*  wv      = (float*)ws;  ws += (size_t)E * 4;

    int nb = (N + 1023) / 1024;

    size_t prep_tot = (size_t)N * K0PAD + HID * K0PAD
                    + (size_t)N_LAYERS * HID * HID + 128 * HID + N;
    prep_kernel<<<(int)((prep_tot + 255) / 256), 256, 0, stream>>>(
        x, lin0_w, W, lin1_w, x_bf, Wt0, Wt, Wt1, counts, N);

    hist_kernel<<<(E + 255) / 256, 256, 0, stream>>>(dst, counts, E);
    scan_phase1<<<nb, 1024, 0, stream>>>(counts, row_ptr, bsum, N);
    scan_phase2<<<1, 64, 0, stream>>>(bsum, nb);
    scan_phase3<<<nb, 1024, 0, stream>>>(row_ptr, cursor, bsum, N, nb);
    scatter_kernel<<<(E + 255) / 256, 256, 0, stream>>>(src, dst, ew, cursor, col, wv, E);

    int mblocks = (N + 127) / 128;
    lin0_mfma<<<dim3(mblocks, 2), 256, 0, stream>>>(x_bf, Wt0, lin0_b, x0_bf, h_bf, N);

    for (int l = 0; l < N_LAYERS; ++l) {
        spmm_mix_kernel<<<(N + 3) / 4, 256, 0, stream>>>(row_ptr, col, wv, h_bf, x0_bf, s_bf, N);
        gemm_mfma_layer<<<mblocks, 512, 0, stream>>>(
            s_bf, Wt + (size_t)l * HID * HID, h_bf, N);
    }

    lin1_mfma<<<mblocks, 256, 0, stream>>>(h_bf, Wt1, lin1_b, out, N);
}

// Round 11
// 289.462 us; speedup vs baseline: 2.3751x; 1.0103x over previous
//
#include <hip/hip_runtime.h>
#include <math.h>

#define IN_F   50
#define HID    256
#define OUT_F  121
#define N_LAYERS 4
#define K0PAD  64

typedef __attribute__((ext_vector_type(8))) short short8;
typedef __attribute__((ext_vector_type(4))) float f32x4;

#define GLOBAL_AS __attribute__((address_space(1)))
#define LDS_AS    __attribute__((address_space(3)))

__device__ __forceinline__ ushort f2bf(float f) {
    union { float f; unsigned u; } c; c.f = f;
    unsigned u = c.u;
    u += 0x7fffu + ((u >> 16) & 1u);
    return (ushort)(u >> 16);
}
__device__ __forceinline__ float bf2f(ushort u) {
    union { unsigned u; float f; } c; c.u = ((unsigned)u) << 16;
    return c.f;
}

// ---------------- prep: weight converts + counts zero ----------------
// Wt per layer: [ts=K/32][kq=0..3][n=0..255][j=0..7], k = ts*32+kq*8+j
__global__ __launch_bounds__(256) void prep_kernel(
        const float* __restrict__ x, const float* __restrict__ w0,
        const float* __restrict__ W, const float* __restrict__ w1,
        ushort* __restrict__ x_bf, ushort* __restrict__ wt0,
        ushort* __restrict__ Wt, ushort* __restrict__ wt1,
        int* __restrict__ counts, int n) {
    long long flat = (long long)blockIdx.x * 256 + threadIdx.x;
    long long r0 = (long long)n * K0PAD;
    if (flat < r0) {
        int nd = (int)(flat >> 6), k = (int)(flat & 63);
        x_bf[flat] = (k < IN_F) ? f2bf(x[(size_t)nd * IN_F + k]) : 0;
        return;
    }
    flat -= r0;
    if (flat < HID * K0PAD) {
        int nn = (int)(flat >> 6), k = (int)(flat & 63);
        wt0[flat] = (k < IN_F) ? f2bf(w0[(size_t)k * HID + nn]) : 0;
        return;
    }
    flat -= HID * K0PAD;
    if (flat < N_LAYERS * HID * HID) {
        int l = (int)(flat >> 16);
        int rem = (int)(flat & 65535);
        int ts = rem >> 13;
        int kq = (rem >> 11) & 3;
        int nn = (rem >> 3) & 255;
        int j  = rem & 7;
        int k  = ts * 32 + kq * 8 + j;
        float beta = logf(0.5f / (float)(l + 1) + 1.0f);
        float v = beta * W[(size_t)l * HID * HID + (size_t)k * HID + nn];
        if (k == nn) v += 1.0f - beta;
        Wt[flat] = f2bf(v);
        return;
    }
    flat -= N_LAYERS * HID * HID;
    if (flat < 128 * HID) {
        int nn = (int)(flat >> 8), k = (int)(flat & 255);
        wt1[flat] = (nn < OUT_F) ? f2bf(w1[(size_t)k * OUT_F + nn]) : 0;
        return;
    }
    flat -= 128 * HID;
    if (flat < n) counts[flat] = 0;
}

// ---------------- CSR build ----------------
__global__ void hist_kernel(const int* __restrict__ dst, int* __restrict__ counts, int E) {
    int e = blockIdx.x * blockDim.x + threadIdx.x;
    if (e < E) atomicAdd(&counts[dst[e]], 1);
}

__global__ void scan_phase1(const int* __restrict__ counts, int* __restrict__ row_ptr,
                            int* __restrict__ bsum, int n) {
    __shared__ int sd[1024];
    int t = threadIdx.x;
    int i = blockIdx.x * 1024 + t;
    int v = (i < n) ? counts[i] : 0;
    sd[t] = v;
    __syncthreads();
    for (int off = 1; off < 1024; off <<= 1) {
        int tmp = (t >= off) ? sd[t - off] : 0;
        __syncthreads();
        sd[t] += tmp;
        __syncthreads();
    }
    if (i < n) row_ptr[i] = sd[t] - v;
    if (t == 1023) bsum[blockIdx.x] = sd[1023];
}

// phase3 with built-in redundant bsum prefix scan (replaces old phase2+phase3)
__global__ void scan_phase3(int* __restrict__ row_ptr, int* __restrict__ cursor,
                            const int* __restrict__ bsum, int n, int nb) {
    __shared__ int pref[129];
    int t = threadIdx.x;
    if (t == 0) {
        int run = 0;
        for (int b = 0; b < nb; ++b) { pref[b] = run; run += bsum[b]; }
        pref[nb] = run;
    }
    __syncthreads();
    int i = blockIdx.x * 1024 + t;
    if (i < n) {
        int v = row_ptr[i] + pref[blockIdx.x];
        row_ptr[i] = v;
        cursor[i]  = v;
    }
    if (blockIdx.x == 0 && t == 0) row_ptr[n] = pref[nb];
}

__global__ void scatter_kernel(const int* __restrict__ src, const int* __restrict__ dst,
                               const float* __restrict__ ew, int* __restrict__ cursor,
                               int* __restrict__ col, float* __restrict__ wv, int E) {
    int e = blockIdx.x * blockDim.x + threadIdx.x;
    if (e < E) {
        int d = dst[e];
        int pos = atomicAdd(&cursor[d], 1);
        col[pos] = src[e];
        wv[pos] = ew[e];
    }
}

// ---------------- lin0 MFMA: x0 = relu(x_bf @ Wt0^T + b), K=64 ----------------
__global__ __launch_bounds__(256) void lin0_mfma(
        const ushort* __restrict__ x_bf, const ushort* __restrict__ wt0,
        const float* __restrict__ b, ushort* __restrict__ x0_bf,
        ushort* __restrict__ h_bf, int M) {
    __shared__ ushort As[4][128][8];
    __shared__ ushort Bs[4][128][8];
    int tid = threadIdx.x;
    int wave = tid >> 6;
    int lane = tid & 63;
    int r16 = lane & 15, q = lane >> 4;
    int bm = blockIdx.x * 128;
    int bn = blockIdx.y * 128;
    int wm = (wave >> 1) * 64, wn = (wave & 1) * 64;

    f32x4 acc[4][4] = {};

    int srow = tid & 127;
    int koff0 = tid >> 7;
    int arow = bm + srow; if (arow >= M) arow = M - 1;
    const ushort* aptr = x_bf + (size_t)arow * K0PAD;
    const ushort* bptr = wt0 + (size_t)(bn + srow) * K0PAD;
    char* AsB = (char*)&As[0][0][0];
    char* BsB = (char*)&Bs[0][0][0];
    int woff = wave * 1024;

    const short8* As8 = (const short8*)&As[0][0][0];
    const short8* Bs8 = (const short8*)&Bs[0][0][0];

    for (int k0 = 0; k0 < K0PAD; k0 += 32) {
        __builtin_amdgcn_global_load_lds((const GLOBAL_AS void*)(aptr + k0 + koff0 * 8),
                                         (LDS_AS void*)(AsB + woff), 16, 0, 0);
        __builtin_amdgcn_global_load_lds((const GLOBAL_AS void*)(aptr + k0 + (koff0 + 2) * 8),
                                         (LDS_AS void*)(AsB + 4096 + woff), 16, 0, 0);
        __builtin_amdgcn_global_load_lds((const GLOBAL_AS void*)(bptr + k0 + koff0 * 8),
                                         (LDS_AS void*)(BsB + woff), 16, 0, 0);
        __builtin_amdgcn_global_load_lds((const GLOBAL_AS void*)(bptr + k0 + (koff0 + 2) * 8),
                                         (LDS_AS void*)(BsB + 4096 + woff), 16, 0, 0);
        __syncthreads();

        short8 av[4], bv[4];
#pragma unroll
        for (int mf = 0; mf < 4; ++mf)
            av[mf] = As8[q * 128 + wm + mf * 16 + r16];
#pragma unroll
        for (int nf = 0; nf < 4; ++nf)
            bv[nf] = Bs8[q * 128 + wn + nf * 16 + r16];
#pragma unroll
        for (int mf = 0; mf < 4; ++mf)
#pragma unroll
            for (int nf = 0; nf < 4; ++nf)
                acc[mf][nf] = __builtin_amdgcn_mfma_f32_16x16x32_bf16(av[mf], bv[nf], acc[mf][nf], 0, 0, 0);
        __syncthreads();
    }

#pragma unroll
    for (int mf = 0; mf < 4; ++mf) {
#pragma unroll
        for (int j = 0; j < 4; ++j) {
            int row = bm + wm + mf * 16 + q * 4 + j;
            if (row >= M) continue;
#pragma unroll
            for (int nf = 0; nf < 4; ++nf) {
                int c = bn + wn + nf * 16 + r16;
                size_t idx = (size_t)row * HID + c;
                ushort v = f2bf(fmaxf(acc[mf][nf][j] + b[c], 0.f));
                x0_bf[idx] = v;
                h_bf[idx]  = v;
            }
        }
    }
}

// -------- SpMM + alpha mix (r4 proven form): wave/node, ushort4/lane, 4-edge unroll ----
__global__ __launch_bounds__(256) void spmm_mix_kernel(
        const int* __restrict__ row_ptr, const int* __restrict__ col,
        const float* __restrict__ wv, const ushort* __restrict__ h_bf,
        const ushort* __restrict__ x0_bf, ushort* __restrict__ s_bf, int n) {
    int node = (blockIdx.x * 256 + threadIdx.x) >> 6;
    if (node >= n) return;
    int lane = threadIdx.x & 63;
    int f0 = lane * 4;
    int beg = row_ptr[node], end = row_ptr[node + 1];
    float a0 = 0.f, a1 = 0.f, a2 = 0.f, a3 = 0.f;
    int e = beg;
    for (; e + 4 <= end; e += 4) {
        int c0 = col[e], c1 = col[e + 1], c2 = col[e + 2], c3 = col[e + 3];
        float w0 = wv[e], w1 = wv[e + 1], w2 = wv[e + 2], w3 = wv[e + 3];
        ushort4 v0 = *reinterpret_cast<const ushort4*>(&h_bf[(size_t)c0 * HID + f0]);
        ushort4 v1 = *reinterpret_cast<const ushort4*>(&h_bf[(size_t)c1 * HID + f0]);
        ushort4 v2 = *reinterpret_cast<const ushort4*>(&h_bf[(size_t)c2 * HID + f0]);
        ushort4 v3 = *reinterpret_cast<const ushort4*>(&h_bf[(size_t)c3 * HID + f0]);
        a0 = fmaf(w0, bf2f(v0.x), a0); a1 = fmaf(w0, bf2f(v0.y), a1);
        a2 = fmaf(w0, bf2f(v0.z), a2); a3 = fmaf(w0, bf2f(v0.w), a3);
        a0 = fmaf(w1, bf2f(v1.x), a0); a1 = fmaf(w1, bf2f(v1.y), a1);
        a2 = fmaf(w1, bf2f(v1.z), a2); a3 = fmaf(w1, bf2f(v1.w), a3);
        a0 = fmaf(w2, bf2f(v2.x), a0); a1 = fmaf(w2, bf2f(v2.y), a1);
        a2 = fmaf(w2, bf2f(v2.z), a2); a3 = fmaf(w2, bf2f(v2.w), a3);
        a0 = fmaf(w3, bf2f(v3.x), a0); a1 = fmaf(w3, bf2f(v3.y), a1);
        a2 = fmaf(w3, bf2f(v3.z), a2); a3 = fmaf(w3, bf2f(v3.w), a3);
    }
    if (e + 2 <= end) {
        int c0 = col[e], c1 = col[e + 1];
        float w0 = wv[e], w1 = wv[e + 1];
        ushort4 v0 = *reinterpret_cast<const ushort4*>(&h_bf[(size_t)c0 * HID + f0]);
        ushort4 v1 = *reinterpret_cast<const ushort4*>(&h_bf[(size_t)c1 * HID + f0]);
        a0 = fmaf(w0, bf2f(v0.x), a0); a1 = fmaf(w0, bf2f(v0.y), a1);
        a2 = fmaf(w0, bf2f(v0.z), a2); a3 = fmaf(w0, bf2f(v0.w), a3);
        a0 = fmaf(w1, bf2f(v1.x), a0); a1 = fmaf(w1, bf2f(v1.y), a1);
        a2 = fmaf(w1, bf2f(v1.z), a2); a3 = fmaf(w1, bf2f(v1.w), a3);
        e += 2;
    }
    if (e < end) {
        int c0 = col[e];
        float w0 = wv[e];
        ushort4 v0 = *reinterpret_cast<const ushort4*>(&h_bf[(size_t)c0 * HID + f0]);
        a0 = fmaf(w0, bf2f(v0.x), a0); a1 = fmaf(w0, bf2f(v0.y), a1);
        a2 = fmaf(w0, bf2f(v0.z), a2); a3 = fmaf(w0, bf2f(v0.w), a3);
    }
    size_t idx = (size_t)node * HID + f0;
    ushort4 xv = *reinterpret_cast<const ushort4*>(&x0_bf[idx]);
    ushort4 r;
    r.x = f2bf(0.9f * a0 + 0.1f * bf2f(xv.x));
    r.y = f2bf(0.9f * a1 + 0.1f * bf2f(xv.y));
    r.z = f2bf(0.9f * a2 + 0.1f * bf2f(xv.z));
    r.w = f2bf(0.9f * a3 + 0.1f * bf2f(xv.w));
    *reinterpret_cast<ushort4*>(&s_bf[idx]) = r;
}

// ------- layer GEMM BM=128 x BN=256 single-pass (r10 proven): used for layers 0,1 -----
__global__ __launch_bounds__(512) void gemm_mfma_layer(
        const ushort* __restrict__ s_bf, const ushort* __restrict__ wt,
        ushort* __restrict__ h_bf, int M) {
    __shared__ ushort As[128 * 32];        // 8 KB
    __shared__ ushort Bs[4 * 256 * 8];     // 16 KB
    int tid = threadIdx.x;
    int wave = tid >> 6;
    int lane = tid & 63;
    int r16 = lane & 15, q = lane >> 4;
    int bm = blockIdx.x * 128;
    int wm = (wave >> 2) * 64, wn = (wave & 3) * 64;

    f32x4 acc[4][4] = {};

    int arow_l = tid >> 2;
    int p = tid & 3;
    int gsrc = p ^ ((arow_l >> 1) & 3);
    int arow = bm + arow_l; if (arow >= M) arow = M - 1;
    const ushort* aptr = s_bf + (size_t)arow * HID;
    char* AsB = (char*)As;
    char* BsB = (char*)Bs;
    const short8* Bs8 = (const short8*)Bs;

    for (int ts = 0; ts < 8; ++ts) {
        __builtin_amdgcn_global_load_lds((const GLOBAL_AS void*)(aptr + ts * 32 + gsrc * 8),
                                         (LDS_AS void*)(AsB + tid * 16), 16, 0, 0);
        __builtin_amdgcn_global_load_lds((const GLOBAL_AS void*)(wt + (size_t)ts * 8192 + tid * 8),
                                         (LDS_AS void*)(BsB + tid * 16), 16, 0, 0);
        __builtin_amdgcn_global_load_lds((const GLOBAL_AS void*)(wt + (size_t)ts * 8192 + (tid + 512) * 8),
                                         (LDS_AS void*)(BsB + (tid + 512) * 16), 16, 0, 0);
        __syncthreads();

        short8 av[4], bv[4];
#pragma unroll
        for (int mf = 0; mf < 4; ++mf) {
            int row = wm + mf * 16 + r16;
            int g = q ^ ((row >> 1) & 3);
            av[mf] = *reinterpret_cast<const short8*>(AsB + row * 64 + g * 16);
        }
#pragma unroll
        for (int nf = 0; nf < 4; ++nf)
            bv[nf] = Bs8[q * 256 + wn + nf * 16 + r16];
#pragma unroll
        for (int mf = 0; mf < 4; ++mf)
#pragma unroll
            for (int nf = 0; nf < 4; ++nf)
                acc[mf][nf] = __builtin_amdgcn_mfma_f32_16x16x32_bf16(av[mf], bv[nf], acc[mf][nf], 0, 0, 0);
        __syncthreads();
    }

#pragma unroll
    for (int mf = 0; mf < 4; ++mf) {
#pragma unroll
        for (int j = 0; j < 4; ++j) {
            int row = bm + wm + mf * 16 + q * 4 + j;
            if (row >= M) continue;
#pragma unroll
            for (int nf = 0; nf < 4; ++nf) {
                int c = wn + nf * 16 + r16;
                size_t idx = (size_t)row * HID + c;
                float v = fmaxf(acc[mf][nf][j] + bf2f(h_bf[idx]), 0.f);
                h_bf[idx] = f2bf(v);
            }
        }
    }
}

// ------- layer GEMM, double-buffered counted-vmcnt variant: used for layers 2,3 -------
// A/B experiment vs gemm_mfma_layer (same math, same swizzle, pipelined staging).
__global__ __launch_bounds__(512) void gemm_mfma_layer_db(
        const ushort* __restrict__ s_bf, const ushort* __restrict__ wt,
        ushort* __restrict__ h_bf, int M) {
    __shared__ ushort As[2][128 * 32];     // 2 x 8 KB
    __shared__ ushort Bs[2][4 * 256 * 8];  // 2 x 16 KB
    int tid = threadIdx.x;
    int wave = tid >> 6;
    int lane = tid & 63;
    int r16 = lane & 15, q = lane >> 4;
    int bm = blockIdx.x * 128;
    int wm = (wave >> 2) * 64, wn = (wave & 3) * 64;

    f32x4 acc[4][4] = {};

    int arow_l = tid >> 2;
    int p = tid & 3;
    int gsrc = p ^ ((arow_l >> 1) & 3);
    int arow = bm + arow_l; if (arow >= M) arow = M - 1;
    const ushort* aptr = s_bf + (size_t)arow * HID;

#define STAGE_DB(buf, ts)                                                                  \
    __builtin_amdgcn_global_load_lds((const GLOBAL_AS void*)(aptr + (ts) * 32 + gsrc * 8), \
                                     (LDS_AS void*)((char*)As[buf] + tid * 16), 16, 0, 0); \
    __builtin_amdgcn_global_load_lds((const GLOBAL_AS void*)(wt + (size_t)(ts) * 8192 + tid * 8), \
                                     (LDS_AS void*)((char*)Bs[buf] + tid * 16), 16, 0, 0); \
    __builtin_amdgcn_global_load_lds((const GLOBAL_AS void*)(wt + (size_t)(ts) * 8192 + (tid + 512) * 8), \
                                     (LDS_AS void*)((char*)Bs[buf] + (tid + 512) * 16), 16, 0, 0);

    STAGE_DB(0, 0);
#pragma unroll
    for (int ts = 0; ts < 8; ++ts) {
        const int cur = ts & 1;
        if (ts < 7) { STAGE_DB(cur ^ 1, ts + 1); }
        if (ts < 7) asm volatile("s_waitcnt vmcnt(3)" ::: "memory");
        else        asm volatile("s_waitcnt vmcnt(0)" ::: "memory");
        __builtin_amdgcn_s_barrier();
        asm volatile("" ::: "memory");

        const char* AsB = (const char*)As[cur];
        const short8* Bs8 = (const short8*)Bs[cur];
        short8 av[4], bv[4];
#pragma unroll
        for (int mf = 0; mf < 4; ++mf) {
            int row = wm + mf * 16 + r16;
            int g = q ^ ((row >> 1) & 3);
            av[mf] = *reinterpret_cast<const short8*>(AsB + row * 64 + g * 16);
        }
#pragma unroll
        for (int nf = 0; nf < 4; ++nf)
            bv[nf] = Bs8[q * 256 + wn + nf * 16 + r16];
#pragma unroll
        for (int mf = 0; mf < 4; ++mf)
#pragma unroll
            for (int nf = 0; nf < 4; ++nf)
                acc[mf][nf] = __builtin_amdgcn_mfma_f32_16x16x32_bf16(av[mf], bv[nf], acc[mf][nf], 0, 0, 0);

        asm volatile("" ::: "memory");
        __builtin_amdgcn_s_barrier();       // everyone done reading buf[cur]
    }
#undef STAGE_DB

#pragma unroll
    for (int mf = 0; mf < 4; ++mf) {
#pragma unroll
        for (int j = 0; j < 4; ++j) {
            int row = bm + wm + mf * 16 + q * 4 + j;
            if (row >= M) continue;
#pragma unroll
            for (int nf = 0; nf < 4; ++nf) {
                int c = wn + nf * 16 + r16;
                size_t idx = (size_t)row * HID + c;
                float v = fmaxf(acc[mf][nf][j] + bf2f(h_bf[idx]), 0.f);
                h_bf[idx] = f2bf(v);
            }
        }
    }
}

// ---------------- MFMA lin1: out = h @ lin1_w + b ----------------
__global__ __launch_bounds__(256) void lin1_mfma(
        const ushort* __restrict__ h_bf, const ushort* __restrict__ wt1,
        const float* __restrict__ b, float* __restrict__ out, int M) {
    __shared__ ushort As[4][128][8];
    __shared__ ushort Bs[4][128][8];
    int tid = threadIdx.x;
    int wave = tid >> 6;
    int lane = tid & 63;
    int r16 = lane & 15, q = lane >> 4;
    int bm = blockIdx.x * 128;
    int wm = (wave >> 1) * 64, wn = (wave & 1) * 64;

    f32x4 acc[4][4] = {};

    int srow = tid & 127;
    int koff0 = tid >> 7;
    int arow = bm + srow; if (arow >= M) arow = M - 1;
    const ushort* aptr = h_bf + (size_t)arow * HID;
    const ushort* bptr = wt1 + (size_t)srow * HID;
    char* AsB = (char*)&As[0][0][0];
    char* BsB = (char*)&Bs[0][0][0];
    int woff = wave * 1024;

    const short8* As8 = (const short8*)&As[0][0][0];
    const short8* Bs8 = (const short8*)&Bs[0][0][0];

    for (int k0 = 0; k0 < HID; k0 += 32) {
        __builtin_amdgcn_global_load_lds((const GLOBAL_AS void*)(aptr + k0 + koff0 * 8),
                                         (LDS_AS void*)(AsB + woff), 16, 0, 0);
        __builtin_amdgcn_global_load_lds((const GLOBAL_AS void*)(aptr + k0 + (koff0 + 2) * 8),
                                         (LDS_AS void*)(AsB + 4096 + woff), 16, 0, 0);
        __builtin_amdgcn_global_load_lds((const GLOBAL_AS void*)(bptr + k0 + koff0 * 8),
                                         (LDS_AS void*)(BsB + woff), 16, 0, 0);
        __builtin_amdgcn_global_load_lds((const GLOBAL_AS void*)(bptr + k0 + (koff0 + 2) * 8),
                                         (LDS_AS void*)(BsB + 4096 + woff), 16, 0, 0);
        __syncthreads();

        short8 av[4], bv[4];
#pragma unroll
        for (int mf = 0; mf < 4; ++mf)
            av[mf] = As8[q * 128 + wm + mf * 16 + r16];
#pragma unroll
        for (int nf = 0; nf < 4; ++nf)
            bv[nf] = Bs8[q * 128 + wn + nf * 16 + r16];
#pragma unroll
        for (int mf = 0; mf < 4; ++mf)
#pragma unroll
            for (int nf = 0; nf < 4; ++nf)
                acc[mf][nf] = __builtin_amdgcn_mfma_f32_16x16x32_bf16(av[mf], bv[nf], acc[mf][nf], 0, 0, 0);
        __syncthreads();
    }

#pragma unroll
    for (int mf = 0; mf < 4; ++mf) {
#pragma unroll
        for (int j = 0; j < 4; ++j) {
            int row = bm + wm + mf * 16 + q * 4 + j;
            if (row >= M) continue;
#pragma unroll
            for (int nf = 0; nf < 4; ++nf) {
                int c = wn + nf * 16 + r16;
                if (c < OUT_F)
                    out[(size_t)row * OUT_F + c] = acc[mf][nf][j] + b[c];
            }
        }
    }
}

extern "C" void kernel_launch(void* const* d_in, const int* in_sizes, int n_in,
                              void* d_out, int out_size, void* d_ws, size_t ws_size,
                              hipStream_t stream) {
    const float* x      = (const float*)d_in[0];
    const int*   ei     = (const int*)d_in[1];
    const float* ew     = (const float*)d_in[2];
    const float* lin0_w = (const float*)d_in[3];
    const float* lin0_b = (const float*)d_in[4];
    const float* W      = (const float*)d_in[5];
    const float* lin1_w = (const float*)d_in[6];
    const float* lin1_b = (const float*)d_in[7];
    float* out = (float*)d_out;

    int N = in_sizes[0] / IN_F;
    int E = in_sizes[2];
    const int* src = ei;
    const int* dst = ei + E;

    char* ws = (char*)d_ws;
    ushort* x0_bf   = (ushort*)ws; ws += (size_t)N * HID * 2;
    ushort* h_bf    = (ushort*)ws; ws += (size_t)N * HID * 2;
    ushort* s_bf    = (ushort*)ws; ws += (size_t)N * HID * 2;
    ushort* x_bf    = (ushort*)ws; ws += (size_t)N * K0PAD * 2;
    ushort* Wt0     = (ushort*)ws; ws += (size_t)HID * K0PAD * 2;
    ushort* Wt      = (ushort*)ws; ws += (size_t)N_LAYERS * HID * HID * 2;
    ushort* Wt1     = (ushort*)ws; ws += (size_t)128 * HID * 2;
    int*    row_ptr = (int*)ws;    ws += (size_t)(N + 1) * 4;
    int*    counts  = (int*)ws;    ws += (size_t)N * 4;
    int*    cursor  = (int*)ws;    ws += (size_t)N * 4;
    int*    bsum    = (int*)ws;    ws += (size_t)128 * 4;
    int*    col     = (int*)ws;    ws += (size_t)E * 4;
    float*  wv      = (float*)ws;  ws += (size_t)E * 4;

    int nb = (N + 1023) / 1024;

    size_t prep_tot = (size_t)N * K0PAD + HID * K0PAD
                    + (size_t)N_LAYERS * HID * HID + 128 * HID + N;
    prep_kernel<<<(int)((prep_tot + 255) / 256), 256, 0, stream>>>(
        x, lin0_w, W, lin1_w, x_bf, Wt0, Wt, Wt1, counts, N);

    hist_kernel<<<(E + 255) / 256, 256, 0, stream>>>(dst, counts, E);
    scan_phase1<<<nb, 1024, 0, stream>>>(counts, row_ptr, bsum, N);
    scan_phase3<<<nb, 1024, 0, stream>>>(row_ptr, cursor, bsum, N, nb);
    scatter_kernel<<<(E + 255) / 256, 256, 0, stream>>>(src, dst, ew, cursor, col, wv, E);

    int mblocks = (N + 127) / 128;
    lin0_mfma<<<dim3(mblocks, 2), 256, 0, stream>>>(x_bf, Wt0, lin0_b, x0_bf, h_bf, N);

    for (int l = 0; l < N_LAYERS; ++l) {
        spmm_mix_kernel<<<(N + 3) / 4, 256, 0, stream>>>(row_ptr, col, wv, h_bf, x0_bf, s_bf, N);
        if (l < 2)
            gemm_mfma_layer<<<mblocks, 512, 0, stream>>>(
                s_bf, Wt + (size_t)l * HID * HID, h_bf, N);
        else
            gemm_mfma_layer_db<<<mblocks, 512, 0, stream>>>(
                s_bf, Wt + (size_t)l * HID * HID, h_bf, N);
    }

    lin1_mfma<<<mblocks, 256, 0, stream>>>(h_bf, Wt1, lin1_b, out, N);
}